// Round 3
// baseline (828.066 us; speedup 1.0000x reference)
//
#include <hip/hip_runtime.h>
#include <stdint.h>

#define L48   48
#define NLOC  2304      // 48*48
#define C3CH  256
#define KDIM  2304      // 256*9
#define BATCH 4
#define PADLOC 2400     // 50 rows * 48

typedef _Float16 half8 __attribute__((ext_vector_type(8)));
typedef float    floatx4 __attribute__((ext_vector_type(4)));
typedef unsigned short ushort8v __attribute__((ext_vector_type(8)));

union H16 { _Float16 f; unsigned short u; };

// ---------------- prep: fp32 image -> channel-last padded split-fp16 (lo = v - h, unscaled) ----
// out[oxIdx][b][loc' = yy*48+x][c], yy in [0,50) meaning y=yy-1, value = img[c][y][x+ox-1] (0 OOB)
__global__ __launch_bounds__(256) void prep_kernel(const float* __restrict__ img,
                                                   unsigned short* __restrict__ out_hi,
                                                   unsigned short* __restrict__ out_lo)
{
    __shared__ unsigned short hi[256 * 50];
    __shared__ unsigned short lo[256 * 50];
    int bid = blockIdx.x;
    int oxIdx = bid / 200;
    int rem   = bid % 200;
    int b     = rem / 50;
    int yy    = rem % 50;
    int kj = oxIdx - 1;
    int y  = yy - 1;
    int t = threadIdx.x;
    bool yok = (unsigned)y < 48u;
    const float* ibase = img + (size_t)b * C3CH * NLOC;
    for (int flat = t; flat < 256 * 48; flat += 256) {
        int c = flat / 48;
        int x = flat - c * 48;
        int xs = x + kj;
        float v = 0.f;
        if (yok && (unsigned)xs < 48u)
            v = ibase[c * NLOC + y * L48 + xs];
        H16 h, l;
        h.f = (_Float16)v;
        float rvv = v - (float)h.f;
        l.f = (_Float16)rvv;
        hi[c * 50 + x] = h.u;
        lo[c * 50 + x] = l.u;
    }
    __syncthreads();
    size_t obase = ((size_t)(oxIdx * 4 + b) * PADLOC + (size_t)yy * 48) * 256;
    for (int flat = t; flat < 256 * 48; flat += 256) {
        int c = flat & 255;
        int x = flat >> 8;
        out_hi[obase + (size_t)x * 256 + c] = hi[c * 50 + x];
        out_lo[obase + (size_t)x * 256 + c] = lo[c * 50 + x];
    }
}

// ---------------- norms from prepped planes: coalesced, one wave per location ----------------
__global__ __launch_bounds__(256) void norm2_kernel(const unsigned short* __restrict__ hi,
                                                    const unsigned short* __restrict__ lo,
                                                    float* __restrict__ inv_norm)
{
    int wid  = (blockIdx.x * 256 + threadIdx.x) >> 6;
    int lane = threadIdx.x & 63;
    if (wid >= BATCH * NLOC) return;
    int b = wid / NLOC;
    int m = wid - b * NLOC;
    int y = m / L48, x = m - y * L48;
    float acc = 0.f;
    for (int o = 0; o < 9; ++o) {
        int dy  = o / 3;
        int dxi = o % 3;
        size_t base = (((size_t)(dxi * 4 + b) * PADLOC + (size_t)(y + dy) * 48 + x) * 256) + lane * 4;
        ushort4 h4 = *(const ushort4*)(hi + base);
        ushort4 l4 = *(const ushort4*)(lo + base);
        #pragma unroll
        for (int c = 0; c < 4; ++c) {
            H16 hh, ll;
            hh.u = (&h4.x)[c];
            ll.u = (&l4.x)[c];
            float v = (float)hh.f + (float)ll.f;
            acc += v * v;
        }
    }
    #pragma unroll
    for (int off = 32; off >= 1; off >>= 1)
        acc += __shfl_xor(acc, off, 64);
    if (lane == 0) {
        float n = fmaxf(sqrtf(acc), 1e-12f);
        inv_norm[wid] = 1.f / n;
    }
}

// ---------------- search: fp16 hi/lo split MFMA, ki-halo staging, ox-outer ----------------
// Block tile: 128 l x 64 m. LDS: A rows l0..l0+223 (48-halo both sides), B rows m0..m0+159.
// 24 stages (3 ox x 8 ch-chunks), 3 ki offsets computed per stage.
__global__ __launch_bounds__(256, 2) void search_mfma(const unsigned short* __restrict__ At_hi,
                                                      const unsigned short* __restrict__ At_lo,
                                                      const unsigned short* __restrict__ Bt_hi,
                                                      const unsigned short* __restrict__ Bt_lo,
                                                      const float* __restrict__ nr_inv,
                                                      unsigned long long* __restrict__ packed)
{
    __shared__ unsigned short lds[30720];       // 61440 B
    unsigned short* sAh = lds;                  // 224*40
    unsigned short* sAl = lds + 8960;
    unsigned short* sBh = lds + 17920;          // 160*40
    unsigned short* sBl = lds + 24320;

    const int tid  = threadIdx.x;
    const int lane = tid & 63;
    const int wr   = (tid >> 7) & 1;   // l-half (0..1)
    const int wc   = (tid >> 6) & 1;   // m-half (0..1)
    const int mrow = lane & 15;
    const int quad = lane >> 4;
    const int koff = quad * 8;

    const int b  = blockIdx.z;
    const int l0 = blockIdx.y * 128;
    const int m0 = blockIdx.x * 64;

    floatx4 acc[4][2];
    #pragma unroll
    for (int i = 0; i < 4; ++i)
        #pragma unroll
        for (int j = 0; j < 2; ++j) acc[i][j] = (floatx4)0.f;

    for (int ox = 0; ox < 3; ++ox) {
        const unsigned short* gAh = At_hi + ((size_t)(ox * 4 + b) * PADLOC + l0) * 256;
        const unsigned short* gAl = At_lo + ((size_t)(ox * 4 + b) * PADLOC + l0) * 256;
        const unsigned short* gBh = Bt_hi + ((size_t)(ox * 4 + b) * PADLOC + m0) * 256;
        const unsigned short* gBl = Bt_lo + ((size_t)(ox * 4 + b) * PADLOC + m0) * 256;

        for (int cc = 0; cc < 8; ++cc) {
            const int c0 = cc * 32;
            __syncthreads();   // previous compute must finish reading LDS
            // stage A: 224 rows x 32 ch  (896 vec8 slots per part)
            #pragma unroll
            for (int j = 0; j < 4; ++j) {
                int s = tid + j * 256;
                if (s < 896) {
                    int row = s >> 2;
                    int g   = (s & 3) * 8;
                    size_t ga = (size_t)row * 256 + c0 + g;
                    int    la = row * 40 + g;
                    *(ushort8v*)(sAh + la) = *(const ushort8v*)(gAh + ga);
                    *(ushort8v*)(sAl + la) = *(const ushort8v*)(gAl + ga);
                }
            }
            // stage B: 160 rows x 32 ch (640 slots per part)
            #pragma unroll
            for (int j = 0; j < 3; ++j) {
                int s = tid + j * 256;
                if (s < 640) {
                    int row = s >> 2;
                    int g   = (s & 3) * 8;
                    size_t ga = (size_t)row * 256 + c0 + g;
                    int    la = row * 40 + g;
                    *(ushort8v*)(sBh + la) = *(const ushort8v*)(gBh + ga);
                    *(ushort8v*)(sBl + la) = *(const ushort8v*)(gBl + ga);
                }
            }
            __syncthreads();

            #pragma unroll
            for (int ki = 0; ki < 3; ++ki) {
                half8 ahf[4], alf[4];
                #pragma unroll
                for (int fi = 0; fi < 4; ++fi) {
                    int ar = wr * 64 + fi * 16 + mrow + 48 * ki;   // 0..223
                    ahf[fi] = *(const half8*)((const _Float16*)sAh + ar * 40 + koff);
                    alf[fi] = *(const half8*)((const _Float16*)sAl + ar * 40 + koff);
                }
                #pragma unroll
                for (int fj = 0; fj < 2; ++fj) {
                    int br = wc * 32 + fj * 16 + mrow + 48 * ki;   // 0..159
                    half8 bhf = *(const half8*)((const _Float16*)sBh + br * 40 + koff);
                    half8 blf = *(const half8*)((const _Float16*)sBl + br * 40 + koff);
                    #pragma unroll
                    for (int fi = 0; fi < 4; ++fi) {
                        acc[fi][fj] = __builtin_amdgcn_mfma_f32_16x16x32_f16(ahf[fi], bhf, acc[fi][fj], 0, 0, 0);
                        acc[fi][fj] = __builtin_amdgcn_mfma_f32_16x16x32_f16(ahf[fi], blf, acc[fi][fj], 0, 0, 0);
                        acc[fi][fj] = __builtin_amdgcn_mfma_f32_16x16x32_f16(alf[fi], bhf, acc[fi][fj], 0, 0, 0);
                    }
                }
            }
        }
    }

    // ---- epilogue: row-normalize, per-column argmax over the block's 128 l's ----
    __syncthreads();
    float* redv = (float*)lds;              // [8][64]
    int*   redi = (int*)(redv + 512);

    float bestv[2];
    int   besti[2];
    #pragma unroll
    for (int fj = 0; fj < 2; ++fj) { bestv[fj] = -1e30f; besti[fj] = 0; }

    #pragma unroll
    for (int fi = 0; fi < 4; ++fi) {
        int rowb = wr * 64 + fi * 16 + quad * 4;
        #pragma unroll
        for (int r = 0; r < 4; ++r) {
            float rv = nr_inv[b * NLOC + l0 + rowb + r];
            #pragma unroll
            for (int fj = 0; fj < 2; ++fj) {
                float v = acc[fi][fj][r] * rv;
                if (v > bestv[fj]) { bestv[fj] = v; besti[fj] = l0 + rowb + r; }
            }
        }
    }

    int cand = wr * 4 + quad;    // 0..7
    #pragma unroll
    for (int fj = 0; fj < 2; ++fj) {
        int col = wc * 32 + fj * 16 + mrow;   // 0..63
        redv[cand * 64 + col] = bestv[fj];
        redi[cand * 64 + col] = besti[fj];
    }
    __syncthreads();
    if (tid < 64) {
        float best = redv[tid];
        int   bi   = redi[tid];
        #pragma unroll
        for (int c = 1; c < 8; ++c) {
            float v  = redv[c * 64 + tid];
            int   i2 = redi[c * 64 + tid];
            if (v > best || (v == best && i2 < bi)) { best = v; bi = i2; }
        }
        unsigned int sv = __float_as_uint(best);
        sv = (sv & 0x80000000u) ? ~sv : (sv | 0x80000000u);
        unsigned long long p = ((unsigned long long)sv << 32)
                             | (unsigned long long)(0xFFFFFFFFu - (unsigned)bi);
        atomicMax(packed + b * NLOC + m0 + tid, p);
    }
}

// ---------------- finalize: unpack S and argmax ----------------
__global__ __launch_bounds__(256) void finalize_kernel(const unsigned long long* __restrict__ packed,
                                                       const float* __restrict__ nl_inv,
                                                       float* __restrict__ S,
                                                       int* __restrict__ Rarg)
{
    int i = blockIdx.x * 256 + threadIdx.x;
    if (i >= BATCH * NLOC) return;
    unsigned long long p = packed[i];
    unsigned int sv   = (unsigned int)(p >> 32);
    unsigned int bits = (sv & 0x80000000u) ? (sv & 0x7FFFFFFFu) : ~sv;
    float val = __uint_as_float(bits);
    int   idx = (int)(0xFFFFFFFFu - (unsigned int)(p & 0xFFFFFFFFu));
    S[i]    = val * nl_inv[i];
    Rarg[i] = idx;
}

// ------------- transfer: fused gather + fold (no im2col materialization) -------------
template<int C, int H, int K, int S, int P>
__global__ __launch_bounds__(256) void transfer_kernel(const float* __restrict__ ref,
                                                       const int* __restrict__ Rarg,
                                                       float* __restrict__ out)
{
    int idx = blockIdx.x * 256 + threadIdx.x;
    if (idx >= BATCH * C * H * H) return;
    int x = idx % H;
    int y = (idx / H) % H;
    int c = (idx / (H * H)) % C;
    int b = idx / (H * H * C);
    int Y = y + P, X = x + P;
    int ylo = Y - K + 1; ylo = (ylo > 0) ? (ylo + S - 1) / S : 0;
    int yhi = Y / S; if (yhi > 47) yhi = 47;
    int xlo = X - K + 1; xlo = (xlo > 0) ? (xlo + S - 1) / S : 0;
    int xhi = X / S; if (xhi > 47) xhi = 47;
    const float* rbase = ref + ((size_t)b * C + c) * H * H;
    const int*   abase = Rarg + b * NLOC;
    float acc = 0.f;
    for (int py = ylo; py <= yhi; ++py) {
        int ki = Y - py * S;
        for (int px = xlo; px <= xhi; ++px) {
            int kj = X - px * S;
            int q  = abase[py * L48 + px];
            int qy = q / L48, qx = q - qy * L48;
            int row = qy * S + ki - P;
            int col = qx * S + kj - P;
            if ((unsigned)row < (unsigned)H && (unsigned)col < (unsigned)H)
                acc += rbase[row * H + col];
        }
    }
    out[idx] = acc * (1.f / 9.f);
}

extern "C" void kernel_launch(void* const* d_in, const int* in_sizes, int n_in,
                              void* d_out, int out_size, void* d_ws, size_t ws_size,
                              hipStream_t stream)
{
    const float* lrsr  = (const float*)d_in[0];
    const float* refsr = (const float*)d_in[1];
    const float* ref1  = (const float*)d_in[2];
    const float* ref2  = (const float*)d_in[3];
    const float* ref3  = (const float*)d_in[4];

    float* S_out  = (float*)d_out;                   // 9216
    float* T3_out = S_out  + BATCH * NLOC;           // 2359296
    float* T2_out = T3_out + BATCH * 256 * 48 * 48;  // 4718592
    float* T1_out = T2_out + BATCH * 128 * 96 * 96;  // 9437184

    char* ws = (char*)d_ws;
    unsigned long long* packed = (unsigned long long*)ws;         // 73728 B
    float* nr_inv = (float*)(ws + 73728);                         // 36864 B
    float* nl_inv = (float*)(ws + 110592);                        // 36864 B
    int*   Rarg   = (int*)(ws + 147456);                          // 36864 B
    const size_t TSZ = (size_t)3 * BATCH * PADLOC * 256;          // 7372800 elements
    unsigned short* A_hi = (unsigned short*)(ws + 184320);
    unsigned short* A_lo = A_hi + TSZ;
    unsigned short* B_hi = A_lo + TSZ;
    unsigned short* B_lo = B_hi + TSZ;

    hipMemsetAsync(packed, 0, BATCH * NLOC * sizeof(unsigned long long), stream);
    prep_kernel<<<dim3(600), 256, 0, stream>>>(refsr, A_hi, A_lo);
    prep_kernel<<<dim3(600), 256, 0, stream>>>(lrsr,  B_hi, B_lo);
    norm2_kernel<<<dim3(BATCH * NLOC / 4), 256, 0, stream>>>(A_hi, A_lo, nr_inv);
    norm2_kernel<<<dim3(BATCH * NLOC / 4), 256, 0, stream>>>(B_hi, B_lo, nl_inv);

    search_mfma<<<dim3(36, 18, BATCH), 256, 0, stream>>>(A_hi, A_lo, B_hi, B_lo, nr_inv, packed);

    finalize_kernel<<<dim3(36), 256, 0, stream>>>(packed, nl_inv, S_out, Rarg);

    transfer_kernel<256,  48,  3, 1, 1><<<dim3(BATCH*256*48*48   / 256), 256, 0, stream>>>(ref3, Rarg, T3_out);
    transfer_kernel<128,  96,  6, 2, 2><<<dim3(BATCH*128*96*96   / 256), 256, 0, stream>>>(ref2, Rarg, T2_out);
    transfer_kernel< 64, 192, 12, 4, 4><<<dim3(BATCH*64*192*192  / 256), 256, 0, stream>>>(ref1, Rarg, T1_out);
}